// Round 11
// baseline (74.101 us; speedup 1.0000x reference)
//
#include <hip/hip_runtime.h>

#define NPIX 9216
#define PLANE 82944           // 288*288
#define W4PL 57600            // float4 per (o,i) weight plane

typedef float f4v __attribute__((ext_vector_type(4)));

__global__ __launch_bounds__(192)
void lfk11(const float* __restrict__ lf, const float* __restrict__ wts,
           const float* __restrict__ bias, float* __restrict__ out)
{
    // per-wave private double-buffered padded weights: 3 wv x 2 buf x (3oc*16px*28)
    __shared__ float ldsW[8064];          // 32256 B

    const int tid  = threadIdx.x;
    const int wv   = tid >> 6;            // i-split wave 0..2
    const int lane = tid & 63;
    const int px   = lane & 15;
    const int b    = lane >> 4;
    const int bid  = blockIdx.x;
    const int swz  = (bid & 7) * 216 + (bid >> 3);   // bijective; og-triples same XCD
    const int tile = swz / 3;
    const int og   = swz - tile * 3;
    const int oh   = tile / 6;
    const int tc   = tile - oh * 6;
    const int g    = tile * 16 + px;
    const int ow   = tc * 16 + px;
    const int y0   = oh * 3 - 2;          // pt = pl = 2, no bottom/right pad
    const int x0   = ow * 3 - 2;
    const int xcl  = (x0 < 0) ? 0 : x0;
    const bool xneg = (x0 < 0);           // only px==0 in tc==0 blocks
    const bool tc0  = (tc == 0);          // block-uniform
    const bool oh0  = (oh == 0);          // block-uniform

    const f4v* __restrict__ w4g = (const f4v*)wts;
    float* const mybase = ldsW + wv * 2688;
    const int i0 = wv * 3;

    f4v sr0, sr1, sr2, sr3, sr4;
    auto stageLoad = [&](int i) {
        #pragma unroll
        for (int j = 0; j < 5; ++j) {
            const int idx = lane + 64 * j;
            if (j < 4 || idx < 300) {
                const int oc  = idx / 100;
                const int rem = idx - oc * 100;
                const f4v v = w4g[(size_t)((og * 3 + oc) * 9 + i) * W4PL + tile * 100 + rem];
                if (j==0) sr0=v; else if (j==1) sr1=v; else if (j==2) sr2=v;
                else if (j==3) sr3=v; else sr4=v;
            }
        }
    };
    auto scatterWrite = [&](int bufofs) {
        #pragma unroll
        for (int j = 0; j < 5; ++j) {
            const int idx = lane + 64 * j;
            if (j < 4 || idx < 300) {
                const int oc  = idx / 100;
                const int rem = idx - oc * 100;
                const int f0  = rem * 4;
                f4v v;
                if (j==0) v=sr0; else if (j==1) v=sr1; else if (j==2) v=sr2;
                else if (j==3) v=sr3; else v=sr4;
                float vv[4] = {v.x, v.y, v.z, v.w};
                #pragma unroll
                for (int q = 0; q < 4; ++q) {
                    const int f = f0 + q, pd = f / 25, k = f - pd * 25;
                    mybase[bufofs + oc * 448 + pd * 28 + k] = vv[q];
                }
            }
        }
    };

    float acc[9];
    #pragma unroll
    for (int t = 0; t < 9; ++t) acc[t] = 0.f;

    // prologue: stage weights for first i of this wave (no barrier: private buffer)
    stageLoad(i0);
    scatterWrite(0);

    #pragma unroll 1
    for (int s = 0; s < 3; ++s) {
        const int i = i0 + s;
        const int bufofs = (s & 1) * 1344;

        // ---- patches for all 3 c upfront (30 batched VMEM instrs) ----
        f4v  Pv[3][5];
        float Pe[3][5];
        #pragma unroll
        for (int c = 0; c < 3; ++c) {
            const float* rb = lf + ((b * 9 + i) * 3 + c) * PLANE + xcl;
            #pragma unroll
            for (int kh = 0; kh < 5; ++kh) {
                const int y = y0 + kh;
                if (!oh0 || y >= 0) {          // block-uniform
                    const float* rp = rb + y * 288;
                    f4v A; __builtin_memcpy(&A, rp, 16);
                    Pv[c][kh] = A;
                    Pe[c][kh] = rp[4];         // x0+4 <= 287: in-bounds
                } else { Pv[c][kh] = (f4v)0.f; Pe[c][kh] = 0.f; }
            }
        }

        // ---- per oc: weights via 6x ds_read_b128 + 1x b32, FMA over 3 c ----
        #pragma unroll
        for (int oc = 0; oc < 3; ++oc) {
            const float* wb = mybase + bufofs + oc * 448 + px * 28;  // 112B-aligned
            const f4v* wq = (const f4v*)wb;
            const f4v u0=wq[0], u1=wq[1], u2=wq[2], u3=wq[3], u4=wq[4], u5=wq[5];
            float wk[25];
            wk[0]=u0.x; wk[1]=u0.y; wk[2]=u0.z; wk[3]=u0.w;
            wk[4]=u1.x; wk[5]=u1.y; wk[6]=u1.z; wk[7]=u1.w;
            wk[8]=u2.x; wk[9]=u2.y; wk[10]=u2.z; wk[11]=u2.w;
            wk[12]=u3.x; wk[13]=u3.y; wk[14]=u3.z; wk[15]=u3.w;
            wk[16]=u4.x; wk[17]=u4.y; wk[18]=u4.z; wk[19]=u4.w;
            wk[20]=u5.x; wk[21]=u5.y; wk[22]=u5.z; wk[23]=u5.w;
            wk[24]=wb[24];
            #pragma unroll
            for (int c = 0; c < 3; ++c) {
                #pragma unroll
                for (int kh = 0; kh < 5; ++kh) {
                    const f4v A = Pv[c][kh];
                    const float e = Pe[c][kh];
                    float q0,q1,q2,q3,q4;
                    if (tc0) {
                        q0 = xneg ? 0.f : A.x;
                        q1 = xneg ? 0.f : A.y;
                        q2 = xneg ? A.x : A.z;
                        q3 = xneg ? A.y : A.w;
                        q4 = xneg ? A.z : e;
                    } else { q0=A.x; q1=A.y; q2=A.z; q3=A.w; q4=e; }
                    const int t = oc * 3 + c;
                    acc[t] = fmaf(wk[kh*5+0], q0, acc[t]);
                    acc[t] = fmaf(wk[kh*5+1], q1, acc[t]);
                    acc[t] = fmaf(wk[kh*5+2], q2, acc[t]);
                    acc[t] = fmaf(wk[kh*5+3], q3, acc[t]);
                    acc[t] = fmaf(wk[kh*5+4], q4, acc[t]);
                }
            }
        }

        // ---- stage next i into the other buffer (no barrier; same-wave order) ----
        if (s < 2) { stageLoad(i + 1); scatterWrite(bufofs ^ 1344); }
    }

    // ---- cross-wave reduction (single barrier) ----
    if (wv != 0) {
        #pragma unroll
        for (int t = 0; t < 9; ++t)
            ldsW[wv * 2688 + lane * 9 + t] = acc[t];
    }
    __syncthreads();

    if (wv == 0) {
        #pragma unroll
        for (int t = 0; t < 9; ++t)
            acc[t] += ldsW[2688 + lane * 9 + t] + ldsW[5376 + lane * 9 + t];
        #pragma unroll
        for (int oc = 0; oc < 3; ++oc) {
            const int o = og * 3 + oc;
            const float bo = bias[o * NPIX + g];
            #pragma unroll
            for (int c = 0; c < 3; ++c) {
                float v = acc[oc * 3 + c] + bo;
                v = fminf(fmaxf(v, 0.f), 1.f);
                out[((b * 9 + o) * 3 + c) * NPIX + g] = v;
            }
        }
    }
}

extern "C" void kernel_launch(void* const* d_in, const int* in_sizes, int n_in,
                              void* d_out, int out_size, void* d_ws, size_t ws_size,
                              hipStream_t stream) {
    const float* lf   = (const float*)d_in[0];
    const float* wts  = (const float*)d_in[1];
    const float* bias = (const float*)d_in[2];
    float* out = (float*)d_out;
    (void)d_ws; (void)ws_size; (void)in_sizes; (void)n_in; (void)out_size;

    dim3 grid(576 * 3);     // 1728 blocks x 3 waves (i-split)
    dim3 block(192);
    lfk11<<<grid, block, 0, stream>>>(lf, wts, bias, out);
}

// Round 12
// 42.707 us; speedup vs baseline: 1.7351x; 1.7351x over previous
//
#include <hip/hip_runtime.h>

#define STN 9
#define CC 3
#define OWN 96
#define NPIX 9216
#define TILE 16
#define OG 3
#define PST 28            // padded weight row stride (floats): 112B -> 16B-aligned rows
#define RSP 56            // patch row span (floats) = 14 float4 (row*56 = row*14 quads: seq writes)
#define NROWS 60          // 4b * 3c * 5kh
#define PLANE4 20736      // 288*288/4
#define ROW4 72           // 288/4
#define ISTEP4 62208      // 3*PLANE4 : f4 step per i in lf
#define LF_F4_LIM 2239488 // total lf floats / 4
#define WISTEP4 57600
#define WOSTEP4 518400    // 9*57600

typedef float f4v __attribute__((ext_vector_type(4)));

__global__ __launch_bounds__(192)
void lfk12(const float* __restrict__ lf, const float* __restrict__ wts,
           const float* __restrict__ bias, float* __restrict__ out)
{
    __shared__ float ldsP[NROWS * RSP];     // 13.44 KB
    __shared__ float ldsW[OG * TILE * PST]; // 5.38 KB (single buf, both barriers protect)

    const int tid = threadIdx.x;
    const int bid = blockIdx.x;
    const int swz = (bid & 7) * 216 + (bid >> 3);   // bijective XCD swizzle
    const int tile = swz / 3;
    const int og   = swz - tile * 3;
    const int oh   = tile / 6;
    const int tc   = tile - oh * 6;
    const int pix  = tid & 15;
    const int bcq  = tid >> 4;              // 0..11
    const int b    = bcq / 3;
    const int c    = bcq - b * 3;
    const int y0   = oh * 3 - 2;            // pt = pl = 2
    const int xa4  = tc * 12 - 1;           // aligned f4 x-origin of staged rows
    const int g    = tile * 16 + pix;

    const f4v* __restrict__ lf4 = (const f4v*)lf;
    const f4v* __restrict__ w4  = (const f4v*)wts;

    // ---- i-independent staging descriptors (R5-proven) ----
    int  pQ[5]; int pG[5]; bool pL[5];
    #pragma unroll
    for (int j = 0; j < 5; ++j) {
        const int idx = tid + 192 * j;
        pQ[j] = -1; pG[j] = 0; pL[j] = false;
        if (idx < 840) {
            const int row = idx / 14, jj = idx - row * 14;
            const int bb  = row / 15, r2 = row - bb * 15;
            const int cc  = r2 / 5,   kh = r2 - cc * 5;
            const int y   = y0 + kh;
            const int xs4 = xa4 + jj;
            pQ[j] = row * RSP + jj * 4;
            if (y >= 0 && xs4 >= 0) {
                pG[j] = (bb * 27 + cc) * PLANE4 + y * ROW4 + xs4;
                pL[j] = true;
            }
        }
    }
    int  wG[2]; int wL[2][4]; bool wV[2];
    #pragma unroll
    for (int j = 0; j < 2; ++j) {
        const int idx = tid + 192 * j;
        wV[j] = (idx < 300);
        wG[j] = 0; wL[j][0]=wL[j][1]=wL[j][2]=wL[j][3]=0;
        if (wV[j]) {
            const int ol = idx / 100, rem = idx - ol * 100;
            wG[j] = (og * 3 + ol) * WOSTEP4 + tile * 100 + rem;
            const int f0 = rem * 4;
            #pragma unroll
            for (int q = 0; q < 4; ++q) {
                const int f = f0 + q, pd = f / 25, k = f - pd * 25;
                wL[j][q] = (ol * TILE + pd) * PST + k;
            }
        }
    }

    f4v pr[5]; f4v wr[2];
    auto load_regs = [&](int i) {
        #pragma unroll
        for (int j = 0; j < 5; ++j) {
            f4v v = (f4v)0.f;
            if (pL[j]) {
                const int gf4 = pG[j] + i * ISTEP4;
                if (gf4 < LF_F4_LIM) v = lf4[gf4];
            }
            pr[j] = v;
        }
        #pragma unroll
        for (int j = 0; j < 2; ++j)
            if (wV[j]) wr[j] = w4[wG[j] + i * WISTEP4];
    };
    auto store_lds = [&]() {
        #pragma unroll
        for (int j = 0; j < 5; ++j)
            if (pQ[j] >= 0) *(f4v*)&ldsP[pQ[j]] = pr[j];
        #pragma unroll
        for (int j = 0; j < 2; ++j)
            if (wV[j]) {
                ldsW[wL[j][0]] = wr[j].x; ldsW[wL[j][1]] = wr[j].y;
                ldsW[wL[j][2]] = wr[j].z; ldsW[wL[j][3]] = wr[j].w;
            }
    };

    float acc[OG] = {0.f, 0.f, 0.f};
    const float* pbase = &ldsP[(b * 3 + c) * 5 * RSP + 2 + pix * 3];

    load_regs(0);
    #pragma unroll 1
    for (int i = 0; i < STN; ++i) {
        __syncthreads();                 // prior compute done, LDS reusable
        store_lds();
        if (i < STN - 1) load_regs(i + 1);  // overlap HBM latency with compute
        __syncthreads();                 // staged data visible

        float p[25];
        #pragma unroll
        for (int kh = 0; kh < 5; ++kh)
            #pragma unroll
            for (int kw = 0; kw < 5; ++kw)
                p[kh * 5 + kw] = pbase[kh * RSP + kw];

        // ---- weights via ds_read_b128 x6 + b32 (was 75x b32 in R5) ----
        #pragma unroll
        for (int oc = 0; oc < OG; ++oc) {
            const float* wrow = &ldsW[(oc * TILE + pix) * PST];  // 112B-aligned
            const f4v* wq = (const f4v*)wrow;
            const f4v u0 = wq[0], u1 = wq[1], u2 = wq[2];
            const f4v u3 = wq[3], u4 = wq[4], u5 = wq[5];
            const float w24 = wrow[24];
            float w[25];
            w[0]=u0.x;  w[1]=u0.y;  w[2]=u0.z;  w[3]=u0.w;
            w[4]=u1.x;  w[5]=u1.y;  w[6]=u1.z;  w[7]=u1.w;
            w[8]=u2.x;  w[9]=u2.y;  w[10]=u2.z; w[11]=u2.w;
            w[12]=u3.x; w[13]=u3.y; w[14]=u3.z; w[15]=u3.w;
            w[16]=u4.x; w[17]=u4.y; w[18]=u4.z; w[19]=u4.w;
            w[20]=u5.x; w[21]=u5.y; w[22]=u5.z; w[23]=u5.w;
            w[24]=w24;
            #pragma unroll
            for (int k = 0; k < 25; ++k)
                acc[oc] = fmaf(w[k], p[k], acc[oc]);
        }
    }

    // ---- epilogue: bias + clip + store ----
    #pragma unroll
    for (int oc = 0; oc < OG; ++oc) {
        const int o = og * 3 + oc;
        float v = acc[oc] + bias[o * NPIX + g];
        v = fminf(fmaxf(v, 0.f), 1.f);
        out[((b * STN + o) * CC + c) * NPIX + g] = v;
    }
}

extern "C" void kernel_launch(void* const* d_in, const int* in_sizes, int n_in,
                              void* d_out, int out_size, void* d_ws, size_t ws_size,
                              hipStream_t stream) {
    const float* lf   = (const float*)d_in[0];
    const float* wts  = (const float*)d_in[1];
    const float* bias = (const float*)d_in[2];
    float* out = (float*)d_out;
    (void)d_ws; (void)ws_size; (void)in_sizes; (void)n_in; (void)out_size;

    dim3 grid(576 * OG);    // 1728 blocks x 3 waves
    dim3 block(192);
    lfk12<<<grid, block, 0, stream>>>(lf, wts, bias, out);
}

// Round 13
// 37.580 us; speedup vs baseline: 1.9718x; 1.1364x over previous
//
#include <hip/hip_runtime.h>

#define STN 9
#define CC 3
#define NPIX 9216
#define TILE 16
#define OG 3
#define PLANE 82944       // 288*288
#define PST 28            // padded weight row stride (floats): 112B, 16B-aligned rows
#define LBUF (OG*TILE*PST)// 1344 floats per buffer
#define WISTEP4 57600     // f4 per (o,i) weight plane
#define WOSTEP4 518400    // 9*57600

typedef float f4v __attribute__((ext_vector_type(4)));

__global__ __launch_bounds__(192)
void lfk13(const float* __restrict__ lf, const float* __restrict__ wts,
           const float* __restrict__ bias, float* __restrict__ out)
{
    __shared__ float ldsW[2][LBUF];         // 10.75 KB double-buffered weights

    const int tid = threadIdx.x;
    const int bid = blockIdx.x;
    const int swz = (bid & 7) * 216 + (bid >> 3);   // bijective XCD swizzle
    const int tile = swz / 3;
    const int og   = swz - tile * 3;
    const int oh   = tile / 6;
    const int tc   = tile - oh * 6;
    const int px   = tid & 15;
    const int bcq  = tid >> 4;              // 0..11
    const int b    = bcq / 3;
    const int c    = bcq - b * 3;
    const int g    = tile * 16 + px;
    const int ow   = tc * 16 + px;
    const int y0   = oh * 3 - 2;            // pt = pl = 2, no bottom/right pad
    const int x0   = ow * 3 - 2;
    const int xcl  = (x0 < 0) ? 0 : x0;
    const bool xneg = (x0 < 0);             // only px==0 in tc==0 blocks
    const bool tc0  = (tc == 0);            // block-uniform
    const bool oh0  = (oh == 0);            // block-uniform

    // ---- weight staging descriptors: 300 f4 over 192 threads (2 slots) ----
    const f4v* __restrict__ w4 = (const f4v*)wts;
    int  wG[2]; int wL[2][4]; bool wV[2];
    #pragma unroll
    for (int j = 0; j < 2; ++j) {
        const int idx = tid + 192 * j;
        wV[j] = (idx < 300);
        wG[j] = 0; wL[j][0]=wL[j][1]=wL[j][2]=wL[j][3]=0;
        if (wV[j]) {
            const int ol = idx / 100, rem = idx - ol * 100;
            wG[j] = (og * 3 + ol) * WOSTEP4 + tile * 100 + rem;
            const int f0 = rem * 4;
            #pragma unroll
            for (int q = 0; q < 4; ++q) {
                const int f = f0 + q, pd = f / 25, k = f - pd * 25;
                wL[j][q] = (ol * TILE + pd) * PST + k;
            }
        }
    }

    f4v wr[2];
    auto sload = [&](int i) {
        #pragma unroll
        for (int j = 0; j < 2; ++j)
            if (wV[j]) wr[j] = w4[wG[j] + i * WISTEP4];
    };
    auto swrite = [&](int buf) {
        float* d = &ldsW[buf][0];
        #pragma unroll
        for (int j = 0; j < 2; ++j)
            if (wV[j]) {
                d[wL[j][0]] = wr[j].x; d[wL[j][1]] = wr[j].y;
                d[wL[j][2]] = wr[j].z; d[wL[j][3]] = wr[j].w;
            }
    };

    // ---- patch registers: direct global, no LDS ----
    f4v  A[5]; float E[5];
    auto loadP = [&](int i) {
        const float* rb = lf + ((b * 9 + i) * 3 + c) * PLANE + xcl;
        #pragma unroll
        for (int kh = 0; kh < 5; ++kh) {
            const int y = y0 + kh;
            if (!oh0 || y >= 0) {           // block-uniform
                const float* rp = rb + y * 288;
                __builtin_memcpy(&A[kh], rp, 16);   // 4B-aligned dwordx4
                E[kh] = rp[4];                      // x0+4 <= 287: in-bounds
            } else { A[kh] = (f4v)0.f; E[kh] = 0.f; }
        }
    };

    float acc[3] = {0.f, 0.f, 0.f};

    sload(0);
    #pragma unroll 1
    for (int i = 0; i < STN; ++i) {
        const int buf = i & 1;
        swrite(buf);                 // stage weights(i); prev readers of buf done
        if (i < STN - 1) sload(i + 1);   // prefetch next weights (VMEM)
        loadP(i);                    // patch loads in flight into the barrier
        __syncthreads();             // ldsW[buf] visible to all waves

        // build 25-float window from regs (edge-correct)
        float q[25];
        #pragma unroll
        for (int kh = 0; kh < 5; ++kh) {
            const f4v a = A[kh]; const float e = E[kh];
            if (tc0) {
                q[kh*5+0] = xneg ? 0.f : a.x;
                q[kh*5+1] = xneg ? 0.f : a.y;
                q[kh*5+2] = xneg ? a.x : a.z;
                q[kh*5+3] = xneg ? a.y : a.w;
                q[kh*5+4] = xneg ? a.z : e;
            } else {
                q[kh*5+0] = a.x; q[kh*5+1] = a.y; q[kh*5+2] = a.z;
                q[kh*5+3] = a.w; q[kh*5+4] = e;
            }
        }

        // weights via 6x ds_read_b128 + 1x b32 per oc
        #pragma unroll
        for (int oc = 0; oc < OG; ++oc) {
            const float* wrow = &ldsW[buf][oc * (TILE*PST) + px * PST];
            const f4v* wq = (const f4v*)wrow;
            const f4v u0 = wq[0], u1 = wq[1], u2 = wq[2];
            const f4v u3 = wq[3], u4 = wq[4], u5 = wq[5];
            const float w24 = wrow[24];
            float s = acc[oc];
            s = fmaf(u0.x, q[0],  s); s = fmaf(u0.y, q[1],  s);
            s = fmaf(u0.z, q[2],  s); s = fmaf(u0.w, q[3],  s);
            s = fmaf(u1.x, q[4],  s); s = fmaf(u1.y, q[5],  s);
            s = fmaf(u1.z, q[6],  s); s = fmaf(u1.w, q[7],  s);
            s = fmaf(u2.x, q[8],  s); s = fmaf(u2.y, q[9],  s);
            s = fmaf(u2.z, q[10], s); s = fmaf(u2.w, q[11], s);
            s = fmaf(u3.x, q[12], s); s = fmaf(u3.y, q[13], s);
            s = fmaf(u3.z, q[14], s); s = fmaf(u3.w, q[15], s);
            s = fmaf(u4.x, q[16], s); s = fmaf(u4.y, q[17], s);
            s = fmaf(u4.z, q[18], s); s = fmaf(u4.w, q[19], s);
            s = fmaf(u5.x, q[20], s); s = fmaf(u5.y, q[21], s);
            s = fmaf(u5.z, q[22], s); s = fmaf(u5.w, q[23], s);
            s = fmaf(w24,  q[24], s);
            acc[oc] = s;
        }
    }

    // ---- epilogue: bias + clip + store ----
    #pragma unroll
    for (int oc = 0; oc < OG; ++oc) {
        const int o = og * 3 + oc;
        float v = acc[oc] + bias[o * NPIX + g];
        v = fminf(fmaxf(v, 0.f), 1.f);
        out[((b * STN + o) * CC + c) * NPIX + g] = v;
    }
}

extern "C" void kernel_launch(void* const* d_in, const int* in_sizes, int n_in,
                              void* d_out, int out_size, void* d_ws, size_t ws_size,
                              hipStream_t stream) {
    const float* lf   = (const float*)d_in[0];
    const float* wts  = (const float*)d_in[1];
    const float* bias = (const float*)d_in[2];
    float* out = (float*)d_out;
    (void)d_ws; (void)ws_size; (void)in_sizes; (void)n_in; (void)out_size;

    dim3 grid(576 * OG);    // 1728 blocks x 3 waves
    dim3 block(192);
    lfk13<<<grid, block, 0, stream>>>(lf, wts, bias, out);
}

// Round 14
// 33.702 us; speedup vs baseline: 2.1987x; 1.1150x over previous
//
#include <hip/hip_runtime.h>

#define NPIX 9216
#define PLANE 82944           // 288*288
#define W4PL 57600            // float4 per (o,i) weight plane

typedef float f4v __attribute__((ext_vector_type(4)));

__global__ __launch_bounds__(192)
void lfk14(const float* __restrict__ lf, const float* __restrict__ wts,
           const float* __restrict__ bias, float* __restrict__ out)
{
    // per-wave private double-buffered padded weights: [wv][buf][3oc*16px*28]
    __shared__ float ldsW[3][2][1344];    // 32.25 KB

    const int tid  = threadIdx.x;
    const int wv   = tid >> 6;            // i-split wave 0..2
    const int lane = tid & 63;
    const int px   = lane & 15;
    const int b    = lane >> 4;           // 0..3
    const int bid  = blockIdx.x;
    const int swz  = (bid & 7) * 216 + (bid >> 3);   // bijective XCD swizzle
    const int tile = swz / 3;
    const int og   = swz - tile * 3;
    const int oh   = tile / 6;
    const int tc   = tile - oh * 6;
    const int g    = tile * 16 + px;
    const int ow   = tc * 16 + px;
    const int y0   = oh * 3 - 2;          // pt = pl = 2, no bottom/right pad
    const int x0   = ow * 3 - 2;
    const int xcl  = (x0 < 0) ? 0 : x0;
    const bool xneg = (x0 < 0);           // only px==0 in tc==0 blocks
    const bool tc0  = (tc == 0);          // block-uniform
    const bool oh0  = (oh == 0);          // block-uniform

    const f4v* __restrict__ w4g = (const f4v*)wts;
    float* const myl = &ldsW[wv][0][0];
    const int i0 = wv * 3;

    // ---- per-wave weight staging: 300 f4 over 64 lanes (5 slots) ----
    f4v sr0, sr1, sr2, sr3, sr4;
    auto stageLoad = [&](int i) {
        #pragma unroll
        for (int j = 0; j < 5; ++j) {
            const int idx = lane + 64 * j;
            if (j < 4 || idx < 300) {
                const int oc  = idx / 100;
                const int rem = idx - oc * 100;
                const f4v v = w4g[(size_t)((og * 3 + oc) * 9 + i) * W4PL + tile * 100 + rem];
                if (j==0) sr0=v; else if (j==1) sr1=v; else if (j==2) sr2=v;
                else if (j==3) sr3=v; else sr4=v;
            }
        }
    };
    auto scatterWrite = [&](int bo) {
        #pragma unroll
        for (int j = 0; j < 5; ++j) {
            const int idx = lane + 64 * j;
            if (j < 4 || idx < 300) {
                const int oc  = idx / 100;
                const int rem = idx - oc * 100;
                const int f0  = rem * 4;
                f4v v;
                if (j==0) v=sr0; else if (j==1) v=sr1; else if (j==2) v=sr2;
                else if (j==3) v=sr3; else v=sr4;
                float vv[4] = {v.x, v.y, v.z, v.w};
                #pragma unroll
                for (int q = 0; q < 4; ++q) {
                    const int f = f0 + q, pd = f / 25, k = f - pd * 25;
                    myl[bo + oc * 448 + pd * 28 + k] = vv[q];
                }
            }
        }
    };

    // ---- patch load: one c at a time into a named 25-float set ----
    auto loadP = [&](f4v (&A)[5], float (&E)[5], int i, int c) {
        const float* rb = lf + ((b * 9 + i) * 3 + c) * PLANE + xcl;
        #pragma unroll
        for (int kh = 0; kh < 5; ++kh) {
            const int y = y0 + kh;
            if (!oh0 || y >= 0) {             // block-uniform
                const float* rp = rb + y * 288;
                __builtin_memcpy(&A[kh], rp, 16);
                E[kh] = rp[4];                // x0+4 <= 287: in-bounds
            } else { A[kh] = (f4v)0.f; E[kh] = 0.f; }
        }
    };

    float wk[3][25];                      // weights resident per i-step
    float acc[3][3] = {{0,0,0},{0,0,0},{0,0,0}};

    auto doFMA = [&](const f4v (&A)[5], const float (&E)[5], int c) {
        #pragma unroll
        for (int kh = 0; kh < 5; ++kh) {
            const f4v a = A[kh]; const float e = E[kh];
            float q0,q1,q2,q3,q4;
            if (tc0) {
                q0 = xneg ? 0.f : a.x;  q1 = xneg ? 0.f : a.y;
                q2 = xneg ? a.x : a.z;  q3 = xneg ? a.y : a.w;
                q4 = xneg ? a.z : e;
            } else { q0=a.x; q1=a.y; q2=a.z; q3=a.w; q4=e; }
            #pragma unroll
            for (int oc = 0; oc < 3; ++oc) {
                acc[oc][c] = fmaf(wk[oc][kh*5+0], q0, acc[oc][c]);
                acc[oc][c] = fmaf(wk[oc][kh*5+1], q1, acc[oc][c]);
                acc[oc][c] = fmaf(wk[oc][kh*5+2], q2, acc[oc][c]);
                acc[oc][c] = fmaf(wk[oc][kh*5+3], q3, acc[oc][c]);
                acc[oc][c] = fmaf(wk[oc][kh*5+4], q4, acc[oc][c]);
            }
        }
    };

    f4v PA[5], PB[5]; float EA[5], EB[5];

    // ---- prologue ----
    stageLoad(i0);
    scatterWrite(0);
    loadP(PA, EA, i0, 0);

    #pragma unroll 1
    for (int s = 0; s < 3; ++s) {
        const int i  = i0 + s;
        const int bo = (s & 1) ? 1344 : 0;

        // weights(i) -> 75 regs: 6x ds_read_b128 + 1x b32 per oc
        #pragma unroll
        for (int oc = 0; oc < 3; ++oc) {
            const float* wr = myl + bo + oc * 448 + px * 28;   // 112B-aligned
            const f4v* wq = (const f4v*)wr;
            const f4v u0=wq[0], u1=wq[1], u2=wq[2], u3=wq[3], u4=wq[4], u5=wq[5];
            wk[oc][0]=u0.x;  wk[oc][1]=u0.y;  wk[oc][2]=u0.z;  wk[oc][3]=u0.w;
            wk[oc][4]=u1.x;  wk[oc][5]=u1.y;  wk[oc][6]=u1.z;  wk[oc][7]=u1.w;
            wk[oc][8]=u2.x;  wk[oc][9]=u2.y;  wk[oc][10]=u2.z; wk[oc][11]=u2.w;
            wk[oc][12]=u3.x; wk[oc][13]=u3.y; wk[oc][14]=u3.z; wk[oc][15]=u3.w;
            wk[oc][16]=u4.x; wk[oc][17]=u4.y; wk[oc][18]=u4.z; wk[oc][19]=u4.w;
            wk[oc][20]=u5.x; wk[oc][21]=u5.y; wk[oc][22]=u5.z; wk[oc][23]=u5.w;
            wk[oc][24]=wr[24];
        }

        loadP(PB, EB, i, 1);            // c=1 in flight under c=0 FMAs
        doFMA(PA, EA, 0);
        loadP(PA, EA, i, 2);            // c=2 in flight under c=1 FMAs
        doFMA(PB, EB, 1);
        if (s < 2) stageLoad(i + 1);    // next-i weights in flight
        doFMA(PA, EA, 2);
        if (s < 2) {
            scatterWrite(bo ^ 1344);    // private buffer: no barrier needed
            loadP(PA, EA, i + 1, 0);    // first c of next step in flight
        }
    }

    // ---- cross-wave reduction (single barrier) ----
    if (wv != 0) {
        #pragma unroll
        for (int oc = 0; oc < 3; ++oc)
            #pragma unroll
            for (int c = 0; c < 3; ++c)
                myl[lane * 9 + oc * 3 + c] = acc[oc][c];
    }
    __syncthreads();

    if (wv == 0) {
        #pragma unroll
        for (int oc = 0; oc < 3; ++oc)
            #pragma unroll
            for (int c = 0; c < 3; ++c)
                acc[oc][c] += ldsW[1][0][lane * 9 + oc * 3 + c]
                            + ldsW[2][0][lane * 9 + oc * 3 + c];
        #pragma unroll
        for (int oc = 0; oc < 3; ++oc) {
            const int o = og * 3 + oc;
            const float bo = bias[o * NPIX + g];
            #pragma unroll
            for (int c = 0; c < 3; ++c) {
                float v = acc[oc][c] + bo;
                v = fminf(fmaxf(v, 0.f), 1.f);
                out[((b * 9 + o) * 3 + c) * NPIX + g] = v;
            }
        }
    }
}

extern "C" void kernel_launch(void* const* d_in, const int* in_sizes, int n_in,
                              void* d_out, int out_size, void* d_ws, size_t ws_size,
                              hipStream_t stream) {
    const float* lf   = (const float*)d_in[0];
    const float* wts  = (const float*)d_in[1];
    const float* bias = (const float*)d_in[2];
    float* out = (float*)d_out;
    (void)d_ws; (void)ws_size; (void)in_sizes; (void)n_in; (void)out_size;

    dim3 grid(576 * 3);     // 1728 blocks x 3 waves (i-split)
    dim3 block(192);
    lfk14<<<grid, block, 0, stream>>>(lf, wts, bias, out);
}

// Round 15
// 33.152 us; speedup vs baseline: 2.2352x; 1.0166x over previous
//
#include <hip/hip_runtime.h>

#define NPIX 9216
#define PLANE 82944           // 288*288
#define W4PL 57600            // float4 per (o,i) weight plane

typedef float f4v __attribute__((ext_vector_type(4)));

__global__ __launch_bounds__(192)
void lfk15(const float* __restrict__ lf, const float* __restrict__ wts,
           const float* __restrict__ bias, float* __restrict__ out)
{
    // per-wave private SINGLE-buffered padded weights: [wv][3oc*16px*28]
    // (same-wave DS ops are in-order: read(i) ... write(i+1) ... read(i+1) is safe)
    __shared__ float ldsW[3][1344];       // 16.13 KB -> ~10 blocks/CU LDS-cap

    const int tid  = threadIdx.x;
    const int wv   = tid >> 6;            // i-split wave 0..2
    const int lane = tid & 63;
    const int px   = lane & 15;
    const int b    = lane >> 4;           // 0..3
    const int bid  = blockIdx.x;
    const int swz  = (bid & 7) * 216 + (bid >> 3);   // bijective XCD swizzle
    const int tile = swz / 3;
    const int og   = swz - tile * 3;
    const int oh   = tile / 6;
    const int tc   = tile - oh * 6;
    const int g    = tile * 16 + px;
    const int ow   = tc * 16 + px;
    const int y0   = oh * 3 - 2;          // pt = pl = 2, no bottom/right pad
    const int x0   = ow * 3 - 2;
    const int xcl  = (x0 < 0) ? 0 : x0;
    const bool xneg = (x0 < 0);           // only px==0 in tc==0 blocks
    const bool tc0  = (tc == 0);          // block-uniform
    const bool oh0  = (oh == 0);          // block-uniform

    const f4v* __restrict__ w4g = (const f4v*)wts;
    float* const myl = &ldsW[wv][0];
    const int i0 = wv * 3;

    // ---- per-wave weight staging: 300 f4 over 64 lanes (5 slots) ----
    f4v sr0, sr1, sr2, sr3, sr4;
    auto stageLoad = [&](int i) {
        #pragma unroll
        for (int j = 0; j < 5; ++j) {
            const int idx = lane + 64 * j;
            if (j < 4 || idx < 300) {
                const int oc  = idx / 100;
                const int rem = idx - oc * 100;
                const f4v v = w4g[(size_t)((og * 3 + oc) * 9 + i) * W4PL + tile * 100 + rem];
                if (j==0) sr0=v; else if (j==1) sr1=v; else if (j==2) sr2=v;
                else if (j==3) sr3=v; else sr4=v;
            }
        }
    };
    auto scatterWrite = [&]() {
        #pragma unroll
        for (int j = 0; j < 5; ++j) {
            const int idx = lane + 64 * j;
            if (j < 4 || idx < 300) {
                const int oc  = idx / 100;
                const int rem = idx - oc * 100;
                const int f0  = rem * 4;
                f4v v;
                if (j==0) v=sr0; else if (j==1) v=sr1; else if (j==2) v=sr2;
                else if (j==3) v=sr3; else v=sr4;
                float vv[4] = {v.x, v.y, v.z, v.w};
                #pragma unroll
                for (int q = 0; q < 4; ++q) {
                    const int f = f0 + q, pd = f / 25, k = f - pd * 25;
                    myl[oc * 448 + pd * 28 + k] = vv[q];
                }
            }
        }
    };

    // ---- patch load: one c at a time into a named 25-float set ----
    auto loadP = [&](f4v (&A)[5], float (&E)[5], int i, int c) {
        const float* rb = lf + ((b * 9 + i) * 3 + c) * PLANE + xcl;
        #pragma unroll
        for (int kh = 0; kh < 5; ++kh) {
            const int y = y0 + kh;
            if (!oh0 || y >= 0) {             // block-uniform
                const float* rp = rb + y * 288;
                __builtin_memcpy(&A[kh], rp, 16);
                E[kh] = rp[4];                // x0+4 <= 287: in-bounds
            } else { A[kh] = (f4v)0.f; E[kh] = 0.f; }
        }
    };

    float wk[3][25];                      // weights resident per i-step
    float acc[3][3] = {{0,0,0},{0,0,0},{0,0,0}};

    auto doFMA = [&](const f4v (&A)[5], const float (&E)[5], int c) {
        #pragma unroll
        for (int kh = 0; kh < 5; ++kh) {
            const f4v a = A[kh]; const float e = E[kh];
            float q0,q1,q2,q3,q4;
            if (tc0) {
                q0 = xneg ? 0.f : a.x;  q1 = xneg ? 0.f : a.y;
                q2 = xneg ? a.x : a.z;  q3 = xneg ? a.y : a.w;
                q4 = xneg ? a.z : e;
            } else { q0=a.x; q1=a.y; q2=a.z; q3=a.w; q4=e; }
            #pragma unroll
            for (int oc = 0; oc < 3; ++oc) {
                acc[oc][c] = fmaf(wk[oc][kh*5+0], q0, acc[oc][c]);
                acc[oc][c] = fmaf(wk[oc][kh*5+1], q1, acc[oc][c]);
                acc[oc][c] = fmaf(wk[oc][kh*5+2], q2, acc[oc][c]);
                acc[oc][c] = fmaf(wk[oc][kh*5+3], q3, acc[oc][c]);
                acc[oc][c] = fmaf(wk[oc][kh*5+4], q4, acc[oc][c]);
            }
        }
    };

    f4v PA[5], PB[5]; float EA[5], EB[5];

    // ---- prologue ----
    stageLoad(i0);
    scatterWrite();
    loadP(PA, EA, i0, 0);

    #pragma unroll 1
    for (int s = 0; s < 3; ++s) {
        const int i = i0 + s;

        // weights(i) -> 75 regs: 6x ds_read_b128 + 1x b32 per oc
        #pragma unroll
        for (int oc = 0; oc < 3; ++oc) {
            const float* wr = myl + oc * 448 + px * 28;   // 112B-aligned
            const f4v* wq = (const f4v*)wr;
            const f4v u0=wq[0], u1=wq[1], u2=wq[2], u3=wq[3], u4=wq[4], u5=wq[5];
            wk[oc][0]=u0.x;  wk[oc][1]=u0.y;  wk[oc][2]=u0.z;  wk[oc][3]=u0.w;
            wk[oc][4]=u1.x;  wk[oc][5]=u1.y;  wk[oc][6]=u1.z;  wk[oc][7]=u1.w;
            wk[oc][8]=u2.x;  wk[oc][9]=u2.y;  wk[oc][10]=u2.z; wk[oc][11]=u2.w;
            wk[oc][12]=u3.x; wk[oc][13]=u3.y; wk[oc][14]=u3.z; wk[oc][15]=u3.w;
            wk[oc][16]=u4.x; wk[oc][17]=u4.y; wk[oc][18]=u4.z; wk[oc][19]=u4.w;
            wk[oc][20]=u5.x; wk[oc][21]=u5.y; wk[oc][22]=u5.z; wk[oc][23]=u5.w;
            wk[oc][24]=wr[24];
        }

        if (s < 2) stageLoad(i + 1);    // issue EARLY: ~225 FMAs of latency cover

        loadP(PB, EB, i, 1);            // c=1 in flight under c=0 FMAs
        doFMA(PA, EA, 0);
        loadP(PA, EA, i, 2);            // c=2 in flight under c=1 FMAs
        doFMA(PB, EB, 1);
        doFMA(PA, EA, 2);

        if (s < 2) {
            scatterWrite();             // single private buffer: in-order DS = safe
            loadP(PA, EA, i + 1, 0);    // first c of next step in flight
        }
    }

    // ---- cross-wave reduction (single barrier) ----
    if (wv != 0) {
        #pragma unroll
        for (int oc = 0; oc < 3; ++oc)
            #pragma unroll
            for (int c = 0; c < 3; ++c)
                myl[lane * 9 + oc * 3 + c] = acc[oc][c];
    }
    __syncthreads();

    if (wv == 0) {
        #pragma unroll
        for (int oc = 0; oc < 3; ++oc)
            #pragma unroll
            for (int c = 0; c < 3; ++c)
                acc[oc][c] += ldsW[1][lane * 9 + oc * 3 + c]
                            + ldsW[2][lane * 9 + oc * 3 + c];
        #pragma unroll
        for (int oc = 0; oc < 3; ++oc) {
            const int o = og * 3 + oc;
            const float bo = bias[o * NPIX + g];
            #pragma unroll
            for (int c = 0; c < 3; ++c) {
                float v = acc[oc][c] + bo;
                v = fminf(fmaxf(v, 0.f), 1.f);
                out[((b * 9 + o) * 3 + c) * NPIX + g] = v;
            }
        }
    }
}

extern "C" void kernel_launch(void* const* d_in, const int* in_sizes, int n_in,
                              void* d_out, int out_size, void* d_ws, size_t ws_size,
                              hipStream_t stream) {
    const float* lf   = (const float*)d_in[0];
    const float* wts  = (const float*)d_in[1];
    const float* bias = (const float*)d_in[2];
    float* out = (float*)d_out;
    (void)d_ws; (void)ws_size; (void)in_sizes; (void)n_in; (void)out_size;

    dim3 grid(576 * 3);     // 1728 blocks x 3 waves (i-split)
    dim3 block(192);
    lfk15<<<grid, block, 0, stream>>>(lf, wts, bias, out);
}